// Round 1
// baseline (1397.957 us; speedup 1.0000x reference)
//
#include <hip/hip_runtime.h>
#include <hip/hip_bf16.h>
#include <hip/hip_fp16.h>

#define B_    8192
#define D_    1024
#define H_    4096
#define DOUT_ 1024
#define E_    8
#define MAXR  17408   // 16384 assignments + 8*128 padding

typedef float    f32x4 __attribute__((ext_vector_type(4)));
typedef _Float16 f16x8 __attribute__((ext_vector_type(8)));
typedef unsigned short u16;
typedef u16      u16x8 __attribute__((ext_vector_type(8)));
typedef u16      u16x4 __attribute__((ext_vector_type(4)));

__device__ __forceinline__ u16 f2h_bits(float f) {
  _Float16 h = (_Float16)f;
  return __builtin_bit_cast(u16, h);
}

// ---- workspace layout (bytes) ----
// meta @0: counts[8] @0, cursors[8] @32, offsets[9] @64, usage[8] float @128
#define OFF_TOPI 512                         // int[16384]
#define OFF_TOPW (512 + 65536)               // float[16384]
#define OFF_SLOT (512 + 2*65536)             // int[16384]
#define OFF_ATOK (512 + 3*65536)             // int[17408]
#define OFF_XG   266752                      // u16[17408*1024] f16
#define OFF_C2   (266752 + 35651584)         // float[17408*1024]
#define OFF_HB   (OFF_C2 + 71303168)         // u16[17408*hc] f16

__global__ void k_init(int* __restrict__ atok, int* __restrict__ meta) {
  int i = blockIdx.x * 256 + threadIdx.x;
  if (i < MAXR) atok[i] = 0;
  if (blockIdx.x == 0 && threadIdx.x < 64) meta[threadIdx.x] = 0; // counts/cursors/offsets/usage
}

__global__ __launch_bounds__(256) void k_gate(
    const float* __restrict__ x, const float* __restrict__ Wg,
    const float* __restrict__ bg, int* __restrict__ counts,
    float* __restrict__ usage, int* __restrict__ topi, float* __restrict__ topw) {
  __shared__ float su[E_];
  if (threadIdx.x < E_) su[threadIdx.x] = 0.f;
  __syncthreads();
  const int lane = threadIdx.x & 63;
  const int b = blockIdx.x * 4 + (threadIdx.x >> 6);
  float p[E_] = {0.f,0.f,0.f,0.f,0.f,0.f,0.f,0.f};
  #pragma unroll
  for (int j = 0; j < 4; ++j) {
    int d = j * 256 + lane * 4;
    float4 xv = *(const float4*)&x[(size_t)b * D_ + d];
    const float* wr = &Wg[(size_t)d * E_];
    #pragma unroll
    for (int c = 0; c < 4; ++c) {
      float xc = reinterpret_cast<const float*>(&xv)[c];
      #pragma unroll
      for (int e = 0; e < E_; ++e) p[e] += xc * wr[c * E_ + e];
    }
  }
  #pragma unroll
  for (int off = 32; off >= 1; off >>= 1)
    #pragma unroll
    for (int e = 0; e < E_; ++e) p[e] += __shfl_xor(p[e], off, 64);
  float mx = -1e30f;
  #pragma unroll
  for (int e = 0; e < E_; ++e) { p[e] += bg[e]; mx = fmaxf(mx, p[e]); }
  // rank on logits (monotone with softmax probs; fp32, first-index tie-break)
  int i0 = 0; float l0 = p[0];
  #pragma unroll
  for (int e = 1; e < E_; ++e) if (p[e] > l0) { l0 = p[e]; i0 = e; }
  int i1 = -1; float l1 = -1e30f;
  #pragma unroll
  for (int e = 0; e < E_; ++e) if (e != i0 && p[e] > l1) { l1 = p[e]; i1 = e; }
  float s = 0.f;
  #pragma unroll
  for (int e = 0; e < E_; ++e) { p[e] = expf(p[e] - mx); s += p[e]; }
  float inv = 1.f / s;
  if (lane == 0) {
    float e0 = expf(l0 - mx), e1 = expf(l1 - mx);
    float wsum = e0 + e1;
    topi[b * 2] = i0; topi[b * 2 + 1] = i1;
    topw[b * 2] = e0 / wsum; topw[b * 2 + 1] = e1 / wsum;
    atomicAdd(&counts[i0], 1);
    atomicAdd(&counts[i1], 1);
    #pragma unroll
    for (int e = 0; e < E_; ++e) atomicAdd(&su[e], p[e] * inv);
  }
  __syncthreads();
  if (threadIdx.x < E_) atomicAdd(&usage[threadIdx.x], su[threadIdx.x]);
}

__global__ void k_scan_aux(const int* __restrict__ counts, int* __restrict__ offsets,
                           const float* __restrict__ usage, float* __restrict__ auxp) {
  if (threadIdx.x == 0) {
    int off = 0;
    for (int e = 0; e < E_; ++e) { offsets[e] = off; off += (counts[e] + 127) & ~127; }
    offsets[E_] = off;
    float aux = 0.f;
    const float lu = logf(1.0f / (float)E_);
    for (int e = 0; e < E_; ++e) {
      float u = usage[e] * (1.0f / (float)B_);
      aux += u * lu - logf(u) * (1.0f / (float)E_);
    }
    *auxp = aux;
  }
}

__global__ void k_scatter(const int* __restrict__ topi, const int* __restrict__ offsets,
                          int* __restrict__ cursors, int* __restrict__ atok,
                          int* __restrict__ slot_of) {
  int b = blockIdx.x * 256 + threadIdx.x;
  if (b >= B_) return;
  #pragma unroll
  for (int k = 0; k < 2; ++k) {
    int e = topi[b * 2 + k];
    int pos = atomicAdd(&cursors[e], 1);
    int slot = offsets[e] + pos;
    atok[slot] = b;
    slot_of[b * 2 + k] = slot;
  }
}

// gather selected rows of x into compact f16 matrix Xg[slot][D_]
__global__ __launch_bounds__(256) void k_gather(const float* __restrict__ x,
                                                const int* __restrict__ atok,
                                                u16* __restrict__ Xg) {
  int slot = blockIdx.x;
  int tok = atok[slot];
  int c = threadIdx.x * 4;
  float4 v = *(const float4*)&x[(size_t)tok * D_ + c];
  const float* vf = reinterpret_cast<const float*>(&v);
  u16x4 o;
  o.x = f2h_bits(vf[0]); o.y = f2h_bits(vf[1]);
  o.z = f2h_bits(vf[2]); o.w = f2h_bits(vf[3]);
  *(u16x4*)&Xg[(size_t)slot * D_ + c] = o;
}

// GEMM1: Hb[slot][hc] = gelu( Xg[slot][:] @ W1[e][:, h0+n] + b1[e][h0+n] )   (f16 out)
__global__ __launch_bounds__(256) void k_gemm1(
    const u16* __restrict__ Xg, const float* __restrict__ W1,
    const float* __restrict__ b1, const int* __restrict__ offsets,
    u16* __restrict__ Hb, int hc, int h0) {
  const int e = blockIdx.x >> 6;
  const int mt = blockIdx.x & 63;
  const int roff = offsets[e];
  const int pn = offsets[e + 1] - roff;
  const int row0 = mt * 128;
  if (row0 >= pn) return;
  const int n0 = blockIdx.y * 128;
  const int tid = threadIdx.x;
  const int lane = tid & 63, wid = tid >> 6;
  const int wr = wid >> 1, wc = wid & 1;

  __shared__ u16 Ab[128][72];
  __shared__ u16 Bb[128][72];

  f32x4 acc[4][4] = {};

  const float* Bsrc = W1 + (size_t)e * D_ * H_ + (size_t)(h0 + n0);
  const u16* Asrc = Xg + (size_t)(roff + row0) * D_;
  const int arow = tid >> 1, ahalf = tid & 1;
  const int bcb = (tid & 31) * 4, brb = (tid >> 5) * 8;

  for (int kk = 0; kk < D_; kk += 64) {
    { // stage A (f16 copy): 128 x 64
      const u16* s = Asrc + (size_t)arow * D_ + kk + ahalf * 32;
      u16x8 v0 = *(const u16x8*)(s);
      u16x8 v1 = *(const u16x8*)(s + 8);
      u16x8 v2 = *(const u16x8*)(s + 16);
      u16x8 v3 = *(const u16x8*)(s + 24);
      *(u16x8*)&Ab[arow][ahalf * 32 + 0] = v0;
      *(u16x8*)&Ab[arow][ahalf * 32 + 8] = v1;
      *(u16x8*)&Ab[arow][ahalf * 32 + 16] = v2;
      *(u16x8*)&Ab[arow][ahalf * 32 + 24] = v3;
    }
    { // stage B (fp32 -> f16, transposed to [n][k]): 64 x 128
      float4 r[8];
      #pragma unroll
      for (int dr = 0; dr < 8; ++dr)
        r[dr] = *(const float4*)&Bsrc[(size_t)(kk + brb + dr) * H_ + bcb];
      #pragma unroll
      for (int dc = 0; dc < 4; ++dc) {
        u16x8 o;
        #pragma unroll
        for (int dr = 0; dr < 8; ++dr)
          o[dr] = f2h_bits(reinterpret_cast<const float*>(&r[dr])[dc]);
        *(u16x8*)&Bb[bcb + dc][brb] = o;
      }
    }
    __syncthreads();
    #pragma unroll
    for (int ks = 0; ks < 2; ++ks) {
      f16x8 af[4], bf[4];
      #pragma unroll
      for (int m = 0; m < 4; ++m)
        af[m] = *(const f16x8*)&Ab[wr * 64 + m * 16 + (lane & 15)][ks * 32 + (lane >> 4) * 8];
      #pragma unroll
      for (int n = 0; n < 4; ++n)
        bf[n] = *(const f16x8*)&Bb[wc * 64 + n * 16 + (lane & 15)][ks * 32 + (lane >> 4) * 8];
      #pragma unroll
      for (int m = 0; m < 4; ++m)
        #pragma unroll
        for (int n = 0; n < 4; ++n)
          acc[m][n] = __builtin_amdgcn_mfma_f32_16x16x32_f16(af[m], bf[n], acc[m][n], 0, 0, 0);
    }
    __syncthreads();
  }
  const int rhi = (lane >> 4) * 4, cix = lane & 15;
  #pragma unroll
  for (int m = 0; m < 4; ++m) {
    #pragma unroll
    for (int n = 0; n < 4; ++n) {
      int lc = wc * 64 + n * 16 + cix;
      float bv = b1[e * H_ + h0 + n0 + lc];
      #pragma unroll
      for (int j = 0; j < 4; ++j) {
        int lr = wr * 64 + m * 16 + rhi + j;
        float v = acc[m][n][j] + bv;
        v = 0.5f * v * (1.0f + erff(v * 0.70710678118654752f));
        Hb[(size_t)(roff + row0 + lr) * hc + (n0 + lc)] = f2h_bits(v);
      }
    }
  }
}

// GEMM2: C2[slot][n] (+)= Hb[slot][:hc] @ W2[e][h0:h0+hc, n]   (fp32 accumulate)
__global__ __launch_bounds__(256) void k_gemm2(
    const u16* __restrict__ Hb, const float* __restrict__ W2,
    const int* __restrict__ offsets, float* __restrict__ C2, int hc, int h0) {
  const int e = blockIdx.x >> 6;
  const int mt = blockIdx.x & 63;
  const int roff = offsets[e];
  const int pn = offsets[e + 1] - roff;
  const int row0 = mt * 128;
  if (row0 >= pn) return;
  const int n0 = blockIdx.y * 128;
  const int tid = threadIdx.x;
  const int lane = tid & 63, wid = tid >> 6;
  const int wr = wid >> 1, wc = wid & 1;
  const int first = (h0 == 0);

  __shared__ u16 Ab[128][72];
  __shared__ u16 Bb[128][72];

  f32x4 acc[4][4] = {};

  const float* Bsrc = W2 + (size_t)e * H_ * DOUT_ + (size_t)h0 * DOUT_ + n0;
  const u16* Asrc = Hb + (size_t)(roff + row0) * hc;
  const int arow = tid >> 1, ahalf = tid & 1;
  const int bcb = (tid & 31) * 4, brb = (tid >> 5) * 8;

  for (int kk = 0; kk < hc; kk += 64) {
    {
      const u16* s = Asrc + (size_t)arow * hc + kk + ahalf * 32;
      u16x8 v0 = *(const u16x8*)(s);
      u16x8 v1 = *(const u16x8*)(s + 8);
      u16x8 v2 = *(const u16x8*)(s + 16);
      u16x8 v3 = *(const u16x8*)(s + 24);
      *(u16x8*)&Ab[arow][ahalf * 32 + 0] = v0;
      *(u16x8*)&Ab[arow][ahalf * 32 + 8] = v1;
      *(u16x8*)&Ab[arow][ahalf * 32 + 16] = v2;
      *(u16x8*)&Ab[arow][ahalf * 32 + 24] = v3;
    }
    {
      float4 r[8];
      #pragma unroll
      for (int dr = 0; dr < 8; ++dr)
        r[dr] = *(const float4*)&Bsrc[(size_t)(kk + brb + dr) * DOUT_ + bcb];
      #pragma unroll
      for (int dc = 0; dc < 4; ++dc) {
        u16x8 o;
        #pragma unroll
        for (int dr = 0; dr < 8; ++dr)
          o[dr] = f2h_bits(reinterpret_cast<const float*>(&r[dr])[dc]);
        *(u16x8*)&Bb[bcb + dc][brb] = o;
      }
    }
    __syncthreads();
    #pragma unroll
    for (int ks = 0; ks < 2; ++ks) {
      f16x8 af[4], bf[4];
      #pragma unroll
      for (int m = 0; m < 4; ++m)
        af[m] = *(const f16x8*)&Ab[wr * 64 + m * 16 + (lane & 15)][ks * 32 + (lane >> 4) * 8];
      #pragma unroll
      for (int n = 0; n < 4; ++n)
        bf[n] = *(const f16x8*)&Bb[wc * 64 + n * 16 + (lane & 15)][ks * 32 + (lane >> 4) * 8];
      #pragma unroll
      for (int m = 0; m < 4; ++m)
        #pragma unroll
        for (int n = 0; n < 4; ++n)
          acc[m][n] = __builtin_amdgcn_mfma_f32_16x16x32_f16(af[m], bf[n], acc[m][n], 0, 0, 0);
    }
    __syncthreads();
  }
  const int rhi = (lane >> 4) * 4, cix = lane & 15;
  #pragma unroll
  for (int m = 0; m < 4; ++m) {
    #pragma unroll
    for (int n = 0; n < 4; ++n) {
      int lc = wc * 64 + n * 16 + cix;
      #pragma unroll
      for (int j = 0; j < 4; ++j) {
        int lr = wr * 64 + m * 16 + rhi + j;
        float* dst = &C2[(size_t)(roff + row0 + lr) * DOUT_ + (n0 + lc)];
        if (first) *dst = acc[m][n][j];
        else       *dst += acc[m][n][j];
      }
    }
  }
}

__global__ __launch_bounds__(256) void k_combine(
    const float* __restrict__ C2, const float* __restrict__ b2,
    const int* __restrict__ topi, const float* __restrict__ topw,
    const int* __restrict__ slot_of, float* __restrict__ out) {
  int b = blockIdx.x;
  int c = threadIdx.x * 4;
  int e0 = topi[b * 2], e1 = topi[b * 2 + 1];
  float w0 = topw[b * 2], w1 = topw[b * 2 + 1];
  int s0 = slot_of[b * 2], s1 = slot_of[b * 2 + 1];
  float4 a0 = *(const float4*)&C2[(size_t)s0 * DOUT_ + c];
  float4 a1 = *(const float4*)&C2[(size_t)s1 * DOUT_ + c];
  float4 g0 = *(const float4*)&b2[(size_t)e0 * DOUT_ + c];
  float4 g1 = *(const float4*)&b2[(size_t)e1 * DOUT_ + c];
  float4 o;
  o.x = w0 * (a0.x + g0.x) + w1 * (a1.x + g1.x);
  o.y = w0 * (a0.y + g0.y) + w1 * (a1.y + g1.y);
  o.z = w0 * (a0.z + g0.z) + w1 * (a1.z + g1.z);
  o.w = w0 * (a0.w + g0.w) + w1 * (a1.w + g1.w);
  *(float4*)&out[(size_t)b * DOUT_ + c] = o;
}

extern "C" void kernel_launch(void* const* d_in, const int* in_sizes, int n_in,
                              void* d_out, int out_size, void* d_ws, size_t ws_size,
                              hipStream_t stream) {
  const float* x  = (const float*)d_in[0];
  const float* Wg = (const float*)d_in[1];
  const float* bg = (const float*)d_in[2];
  const float* W1 = (const float*)d_in[3];
  const float* b1 = (const float*)d_in[4];
  const float* W2 = (const float*)d_in[5];
  const float* b2 = (const float*)d_in[6];
  float* out = (float*)d_out;

  char* ws = (char*)d_ws;
  int*   counts  = (int*)(ws + 0);
  int*   cursors = (int*)(ws + 32);
  int*   offsets = (int*)(ws + 64);
  float* usage   = (float*)(ws + 128);
  int*   topi    = (int*)(ws + OFF_TOPI);
  float* topw    = (float*)(ws + OFF_TOPW);
  int*   slot_of = (int*)(ws + OFF_SLOT);
  int*   atok    = (int*)(ws + OFF_ATOK);
  u16*   Xg      = (u16*)(ws + OFF_XG);
  float* C2      = (float*)(ws + OFF_C2);
  u16*   Hb      = (u16*)(ws + OFF_HB);

  // pick largest H-chunk that fits the workspace
  int hc = 128;
  for (int c = 4096; c >= 128; c >>= 1)
    if ((size_t)OFF_HB + (size_t)MAXR * c * 2 <= ws_size) { hc = c; break; }

  k_init<<<(MAXR + 255) / 256, 256, 0, stream>>>(atok, (int*)ws);
  k_gate<<<B_ / 4, 256, 0, stream>>>(x, Wg, bg, counts, usage, topi, topw);
  k_scan_aux<<<1, 64, 0, stream>>>(counts, offsets, usage, out + (size_t)B_ * DOUT_);
  k_scatter<<<B_ / 256, 256, 0, stream>>>(topi, offsets, cursors, atok, slot_of);
  k_gather<<<MAXR, 256, 0, stream>>>(x, atok, Xg);
  for (int h0 = 0; h0 < H_; h0 += hc) {
    k_gemm1<<<dim3(E_ * 64, hc / 128), 256, 0, stream>>>(Xg, W1, b1, offsets, Hb, hc, h0);
    k_gemm2<<<dim3(E_ * 64, DOUT_ / 128), 256, 0, stream>>>(Hb, W2, offsets, C2, hc, h0);
  }
  k_combine<<<B_, 256, 0, stream>>>(C2, b2, topi, topw, slot_of, out);
}

// Round 2
// 1327.439 us; speedup vs baseline: 1.0531x; 1.0531x over previous
//
#include <hip/hip_runtime.h>
#include <hip/hip_bf16.h>
#include <hip/hip_fp16.h>

#define B_    8192
#define D_    1024
#define H_    4096
#define DOUT_ 1024
#define E_    8
#define MAXR  17408   // 16384 assignments + 8*128 padding

typedef float    f32x4 __attribute__((ext_vector_type(4)));
typedef _Float16 f16x8 __attribute__((ext_vector_type(8)));
typedef unsigned short u16;
typedef u16      u16x8 __attribute__((ext_vector_type(8)));
typedef u16      u16x4 __attribute__((ext_vector_type(4)));
typedef unsigned int u32;

__device__ __forceinline__ u16 f2h_bits(float f) {
  _Float16 h = (_Float16)f;
  return __builtin_bit_cast(u16, h);
}

// ---- workspace layout (bytes) ----
// meta @0: counts[8] @0, cursors[8] @32, offsets[9] @64, usage[8] float @128
#define OFF_TOPI 512                       // int[16384]
#define OFF_TOPW (OFF_TOPI + 65536)        // float[16384]
#define OFF_ATOK (OFF_TOPW + 65536)        // int[17408]
#define OFF_WSL  (OFF_ATOK + 69632)        // float[17408]
#define OFF_XG   524288                    // u16[17408*1024] f16 (dead after gemm1)
#define OFF_W1T  (OFF_XG + 35651584)       // u16[8*4096*1024] f16 (dead after gemm1)
#define OFF_W2T  OFF_XG                    // u16[8*1024*4096] f16, ALIASES Xg+W1t (built after gemm1)
#define OFF_HB   (OFF_W1T + 67108864)      // u16[17408*4096] f16
// end = OFF_HB + 142606336 = 245,891,072 bytes  (<= 249.8MB proven available in round 1)

__global__ void k_zero_out(float* __restrict__ out) {
  size_t i = (size_t)(blockIdx.x * 256 + threadIdx.x) * 4;
  *(f32x4*)&out[i] = (f32x4){0.f, 0.f, 0.f, 0.f};
}

__global__ void k_init(int* __restrict__ atok, float* __restrict__ wslot,
                       int* __restrict__ meta) {
  int i = blockIdx.x * 256 + threadIdx.x;
  if (i < MAXR) { atok[i] = 0; wslot[i] = 0.f; }
  if (blockIdx.x == 0 && threadIdx.x < 64) meta[threadIdx.x] = 0;
}

__global__ __launch_bounds__(256) void k_gate(
    const float* __restrict__ x, const float* __restrict__ Wg,
    const float* __restrict__ bg, int* __restrict__ counts,
    float* __restrict__ usage, int* __restrict__ topi, float* __restrict__ topw) {
  __shared__ float su[E_];
  if (threadIdx.x < E_) su[threadIdx.x] = 0.f;
  __syncthreads();
  const int lane = threadIdx.x & 63;
  const int b = blockIdx.x * 4 + (threadIdx.x >> 6);
  float p[E_] = {0.f,0.f,0.f,0.f,0.f,0.f,0.f,0.f};
  #pragma unroll
  for (int j = 0; j < 4; ++j) {
    int d = j * 256 + lane * 4;
    float4 xv = *(const float4*)&x[(size_t)b * D_ + d];
    const float* wr = &Wg[(size_t)d * E_];
    #pragma unroll
    for (int c = 0; c < 4; ++c) {
      float xc = reinterpret_cast<const float*>(&xv)[c];
      #pragma unroll
      for (int e = 0; e < E_; ++e) p[e] += xc * wr[c * E_ + e];
    }
  }
  #pragma unroll
  for (int off = 32; off >= 1; off >>= 1)
    #pragma unroll
    for (int e = 0; e < E_; ++e) p[e] += __shfl_xor(p[e], off, 64);
  float mx = -1e30f;
  #pragma unroll
  for (int e = 0; e < E_; ++e) { p[e] += bg[e]; mx = fmaxf(mx, p[e]); }
  int i0 = 0; float l0 = p[0];
  #pragma unroll
  for (int e = 1; e < E_; ++e) if (p[e] > l0) { l0 = p[e]; i0 = e; }
  int i1 = -1; float l1 = -1e30f;
  #pragma unroll
  for (int e = 0; e < E_; ++e) if (e != i0 && p[e] > l1) { l1 = p[e]; i1 = e; }
  float s = 0.f;
  #pragma unroll
  for (int e = 0; e < E_; ++e) { p[e] = expf(p[e] - mx); s += p[e]; }
  float inv = 1.f / s;
  if (lane == 0) {
    float e0 = expf(l0 - mx), e1 = expf(l1 - mx);
    float wsum = e0 + e1;
    topi[b * 2] = i0; topi[b * 2 + 1] = i1;
    topw[b * 2] = e0 / wsum; topw[b * 2 + 1] = e1 / wsum;
    atomicAdd(&counts[i0], 1);
    atomicAdd(&counts[i1], 1);
    #pragma unroll
    for (int e = 0; e < E_; ++e) atomicAdd(&su[e], p[e] * inv);
  }
  __syncthreads();
  if (threadIdx.x < E_) atomicAdd(&usage[threadIdx.x], su[threadIdx.x]);
}

__global__ void k_scan_aux(const int* __restrict__ counts, int* __restrict__ offsets,
                           const float* __restrict__ usage, float* __restrict__ auxp) {
  if (threadIdx.x == 0) {
    int off = 0;
    for (int e = 0; e < E_; ++e) { offsets[e] = off; off += (counts[e] + 127) & ~127; }
    offsets[E_] = off;
    float aux = 0.f;
    const float lu = logf(1.0f / (float)E_);
    for (int e = 0; e < E_; ++e) {
      float u = usage[e] * (1.0f / (float)B_);
      aux += u * lu - logf(u) * (1.0f / (float)E_);
    }
    *auxp = aux;
  }
}

__global__ void k_scatter(const int* __restrict__ topi, const float* __restrict__ topw,
                          const int* __restrict__ offsets, int* __restrict__ cursors,
                          int* __restrict__ atok, float* __restrict__ wslot) {
  int b = blockIdx.x * 256 + threadIdx.x;
  if (b >= B_) return;
  #pragma unroll
  for (int k = 0; k < 2; ++k) {
    int e = topi[b * 2 + k];
    int pos = atomicAdd(&cursors[e], 1);
    int slot = offsets[e] + pos;
    atok[slot] = b;
    wslot[slot] = topw[b * 2 + k];
  }
}

// gather selected rows of x into compact f16 matrix Xg[slot][D_]
__global__ __launch_bounds__(256) void k_gather(const float* __restrict__ x,
                                                const int* __restrict__ atok,
                                                u16* __restrict__ Xg) {
  int slot = blockIdx.x;
  int tok = atok[slot];
  int c = threadIdx.x * 4;
  float4 v = *(const float4*)&x[(size_t)tok * D_ + c];
  const float* vf = reinterpret_cast<const float*>(&v);
  u16x4 o;
  o.x = f2h_bits(vf[0]); o.y = f2h_bits(vf[1]);
  o.z = f2h_bits(vf[2]); o.w = f2h_bits(vf[3]);
  *(u16x4*)&Xg[(size_t)slot * D_ + c] = o;
}

// convert + transpose: src [E][K][N] fp32  ->  dst [E][N][K] f16. 64x64 tiles.
__global__ __launch_bounds__(256) void k_cvt_t(const float* __restrict__ src,
                                               u16* __restrict__ dst, int K, int N) {
  const int e = blockIdx.z;
  const int kt = blockIdx.x * 64;
  const int nt = blockIdx.y * 64;
  __shared__ u16 t[64][68];
  const float* s = src + (size_t)e * K * N;
  u16* d = dst + (size_t)e * N * K;
  const int tr = threadIdx.x >> 4;   // 0..15
  const int tc = threadIdx.x & 15;   // 0..15
  #pragma unroll
  for (int i = 0; i < 4; ++i) {
    int k = tr + i * 16;
    float4 v = *(const float4*)&s[(size_t)(kt + k) * N + nt + tc * 4];
    t[k][tc*4+0] = f2h_bits(v.x); t[k][tc*4+1] = f2h_bits(v.y);
    t[k][tc*4+2] = f2h_bits(v.z); t[k][tc*4+3] = f2h_bits(v.w);
  }
  __syncthreads();
  #pragma unroll
  for (int i = 0; i < 4; ++i) {
    int n = tr + i * 16;
    u16x4 o;
    o.x = t[tc*4+0][n]; o.y = t[tc*4+1][n];
    o.z = t[tc*4+2][n]; o.w = t[tc*4+3][n];
    *(u16x4*)&d[(size_t)(nt + n) * K + kt + tc * 4] = o;
  }
}

#define GLDS(g, l) __builtin_amdgcn_global_load_lds( \
    (const u32 __attribute__((address_space(1)))*)(g), \
    (u32 __attribute__((address_space(3)))*)(l), 16, 0, 0)

// GEMM1: Hb[slot][n] = gelu( Xg[slot][:] @ W1t[e][n][:]^T + b1[e][n] )   (f16 out)
// m97 structure: 128x128 tile, BK=64, global_load_lds w16, linear LDS.
__global__ __launch_bounds__(256) void k_gemm1(
    const u16* __restrict__ Xg, const u16* __restrict__ W1t,
    const float* __restrict__ b1, const int* __restrict__ offsets,
    u16* __restrict__ Hb) {
  const int e  = blockIdx.x >> 6;
  const int mt = blockIdx.x & 63;
  const int roff = offsets[e];
  const int pn = offsets[e + 1] - roff;
  const int row0 = mt * 128;
  if (row0 >= pn) return;
  const int n0 = blockIdx.y * 128;
  const int tid = threadIdx.x, lane = tid & 63, wid = tid >> 6;
  const int wr = wid >> 1, wc = wid & 1;
  __shared__ u16 As[128 * 64];
  __shared__ u16 Bs[128 * 64];
  f32x4 acc[4][4] = {};
  const u16* Ap = Xg + (size_t)(roff + row0) * D_;
  const u16* Bp = W1t + (size_t)e * H_ * D_ + (size_t)n0 * D_;
  const int srow = lane >> 3;        // 0..7
  const int scol = (lane & 7) * 8;   // f16 col within 64
  for (int kk = 0; kk < D_; kk += 64) {
    #pragma unroll
    for (int c = 0; c < 4; ++c) {
      int seg = wid * 4 + c;  // 0..15, wave-uniform
      GLDS(Ap + (size_t)(seg * 8 + srow) * D_ + kk + scol, &As[seg * 512]);
      GLDS(Bp + (size_t)(seg * 8 + srow) * D_ + kk + scol, &Bs[seg * 512]);
    }
    __syncthreads();
    #pragma unroll
    for (int ks = 0; ks < 2; ++ks) {
      f16x8 af[4], bf[4];
      #pragma unroll
      for (int m = 0; m < 4; ++m)
        af[m] = *(const f16x8*)&As[(wr * 64 + m * 16 + (lane & 15)) * 64 + ks * 32 + (lane >> 4) * 8];
      #pragma unroll
      for (int n = 0; n < 4; ++n)
        bf[n] = *(const f16x8*)&Bs[(wc * 64 + n * 16 + (lane & 15)) * 64 + ks * 32 + (lane >> 4) * 8];
      #pragma unroll
      for (int m = 0; m < 4; ++m)
        #pragma unroll
        for (int n = 0; n < 4; ++n)
          acc[m][n] = __builtin_amdgcn_mfma_f32_16x16x32_f16(af[m], bf[n], acc[m][n], 0, 0, 0);
    }
    __syncthreads();
  }
  const int rhi = (lane >> 4) * 4, cix = lane & 15;
  #pragma unroll
  for (int n = 0; n < 4; ++n) {
    int lc = wc * 64 + n * 16 + cix;
    float bv = b1[e * H_ + n0 + lc];
    #pragma unroll
    for (int m = 0; m < 4; ++m) {
      #pragma unroll
      for (int j = 0; j < 4; ++j) {
        int lr = wr * 64 + m * 16 + rhi + j;
        float v = acc[m][n][j] + bv;
        v = 0.5f * v * (1.0f + erff(v * 0.70710678118654752f));
        Hb[(size_t)(roff + row0 + lr) * H_ + (n0 + lc)] = f2h_bits(v);
      }
    }
  }
}

// GEMM2: out[tok][n] += wslot * ( Hb[slot][:] @ W2t[e][n][:]^T + b2[e][n] )
__global__ __launch_bounds__(256) void k_gemm2(
    const u16* __restrict__ Hb, const u16* __restrict__ W2t,
    const float* __restrict__ b2, const int* __restrict__ offsets,
    const int* __restrict__ atok, const float* __restrict__ wslot,
    float* __restrict__ out) {
  const int e  = blockIdx.x >> 6;
  const int mt = blockIdx.x & 63;
  const int roff = offsets[e];
  const int pn = offsets[e + 1] - roff;
  const int row0 = mt * 128;
  if (row0 >= pn) return;
  const int n0 = blockIdx.y * 128;
  const int tid = threadIdx.x, lane = tid & 63, wid = tid >> 6;
  const int wr = wid >> 1, wc = wid & 1;
  __shared__ u16 As[128 * 64];
  __shared__ u16 Bs[128 * 64];
  f32x4 acc[4][4] = {};
  const u16* Ap = Hb + (size_t)(roff + row0) * H_;
  const u16* Bp = W2t + (size_t)e * DOUT_ * H_ + (size_t)n0 * H_;
  const int srow = lane >> 3;
  const int scol = (lane & 7) * 8;
  for (int kk = 0; kk < H_; kk += 64) {
    #pragma unroll
    for (int c = 0; c < 4; ++c) {
      int seg = wid * 4 + c;
      GLDS(Ap + (size_t)(seg * 8 + srow) * H_ + kk + scol, &As[seg * 512]);
      GLDS(Bp + (size_t)(seg * 8 + srow) * H_ + kk + scol, &Bs[seg * 512]);
    }
    __syncthreads();
    #pragma unroll
    for (int ks = 0; ks < 2; ++ks) {
      f16x8 af[4], bf[4];
      #pragma unroll
      for (int m = 0; m < 4; ++m)
        af[m] = *(const f16x8*)&As[(wr * 64 + m * 16 + (lane & 15)) * 64 + ks * 32 + (lane >> 4) * 8];
      #pragma unroll
      for (int n = 0; n < 4; ++n)
        bf[n] = *(const f16x8*)&Bs[(wc * 64 + n * 16 + (lane & 15)) * 64 + ks * 32 + (lane >> 4) * 8];
      #pragma unroll
      for (int m = 0; m < 4; ++m)
        #pragma unroll
        for (int n = 0; n < 4; ++n)
          acc[m][n] = __builtin_amdgcn_mfma_f32_16x16x32_f16(af[m], bf[n], acc[m][n], 0, 0, 0);
    }
    __syncthreads();
  }
  const int rhi = (lane >> 4) * 4, cix = lane & 15;
  float bv[4];
  #pragma unroll
  for (int n = 0; n < 4; ++n) bv[n] = b2[e * DOUT_ + n0 + wc * 64 + n * 16 + cix];
  #pragma unroll
  for (int m = 0; m < 4; ++m) {
    #pragma unroll
    for (int j = 0; j < 4; ++j) {
      int lr = wr * 64 + m * 16 + rhi + j;
      int slot = roff + row0 + lr;
      float w = wslot[slot];
      if (w == 0.f) continue;   // padding slot
      int tok = atok[slot];
      float* orow = out + (size_t)tok * DOUT_ + n0;
      #pragma unroll
      for (int n = 0; n < 4; ++n) {
        int lc = wc * 64 + n * 16 + cix;
        atomicAdd(&orow[lc], w * (acc[m][n][j] + bv[n]));
      }
    }
  }
}

extern "C" void kernel_launch(void* const* d_in, const int* in_sizes, int n_in,
                              void* d_out, int out_size, void* d_ws, size_t ws_size,
                              hipStream_t stream) {
  const float* x  = (const float*)d_in[0];
  const float* Wg = (const float*)d_in[1];
  const float* bg = (const float*)d_in[2];
  const float* W1 = (const float*)d_in[3];
  const float* b1 = (const float*)d_in[4];
  const float* W2 = (const float*)d_in[5];
  const float* b2 = (const float*)d_in[6];
  float* out = (float*)d_out;

  char* ws = (char*)d_ws;
  int*   counts  = (int*)(ws + 0);
  int*   cursors = (int*)(ws + 32);
  int*   offsets = (int*)(ws + 64);
  float* usage   = (float*)(ws + 128);
  int*   topi    = (int*)(ws + OFF_TOPI);
  float* topw    = (float*)(ws + OFF_TOPW);
  int*   atok    = (int*)(ws + OFF_ATOK);
  float* wslot   = (float*)(ws + OFF_WSL);
  u16*   Xg      = (u16*)(ws + OFF_XG);
  u16*   W1t     = (u16*)(ws + OFF_W1T);
  u16*   W2t     = (u16*)(ws + OFF_W2T);   // aliases Xg/W1t, built after gemm1
  u16*   Hb      = (u16*)(ws + OFF_HB);

  k_zero_out<<<B_ * DOUT_ / 1024, 256, 0, stream>>>(out);
  k_init<<<(MAXR + 255) / 256, 256, 0, stream>>>(atok, wslot, (int*)ws);
  k_gate<<<B_ / 4, 256, 0, stream>>>(x, Wg, bg, counts, usage, topi, topw);
  k_scan_aux<<<1, 64, 0, stream>>>(counts, offsets, usage, out + (size_t)B_ * DOUT_);
  k_scatter<<<B_ / 256, 256, 0, stream>>>(topi, topw, offsets, cursors, atok, wslot);
  k_gather<<<MAXR, 256, 0, stream>>>(x, atok, Xg);
  k_cvt_t<<<dim3(D_ / 64, H_ / 64, E_), 256, 0, stream>>>(W1, W1t, D_, H_);
  k_gemm1<<<dim3(E_ * 64, H_ / 128), 256, 0, stream>>>(Xg, W1t, b1, offsets, Hb);
  k_cvt_t<<<dim3(H_ / 64, DOUT_ / 64, E_), 256, 0, stream>>>(W2, W2t, H_, DOUT_);
  k_gemm2<<<dim3(E_ * 64, DOUT_ / 128), 256, 0, stream>>>(Hb, W2t, b2, offsets, atok, wslot, out);
}

// Round 4
// 1213.352 us; speedup vs baseline: 1.1521x; 1.0940x over previous
//
#include <hip/hip_runtime.h>
#include <hip/hip_bf16.h>
#include <hip/hip_fp16.h>

#define B_    8192
#define D_    1024
#define H_    4096
#define DOUT_ 1024
#define E_    8
#define MAXR  17408   // 16384 assignments + 8*128 padding

typedef float    f32x4 __attribute__((ext_vector_type(4)));
typedef _Float16 f16x8 __attribute__((ext_vector_type(8)));
typedef unsigned short u16;
typedef u16      u16x8 __attribute__((ext_vector_type(8)));
typedef u16      u16x4 __attribute__((ext_vector_type(4)));
typedef unsigned int u32;

__device__ __forceinline__ u16 f2h_bits(float f) {
  _Float16 h = (_Float16)f;
  return __builtin_bit_cast(u16, h);
}

// tanh-form gelu (max abs err vs erf-gelu ~3e-4; threshold margin 4x)
__device__ __forceinline__ float gelu_f(float v) {
  float z = 0.7978845608028654f * (v + 0.044715f * v * v * v);
  float ez = __expf(2.f * z);
  float th = 1.f - 2.f / (ez + 1.f);
  return 0.5f * v * (1.f + th);
}

// ---- workspace layout (bytes) ----
#define OFF_TOPI 512                       // int[16384]
#define OFF_TOPW (OFF_TOPI + 65536)        // float[16384]
#define OFF_ATOK (OFF_TOPW + 65536)        // int[17408]
#define OFF_WSL  (OFF_ATOK + 69632)        // float[17408]
#define OFF_XG   524288                    // u16[17408*1024] f16 (dead after gemm1)
#define OFF_W1T  (OFF_XG + 35651584)       // u16[8*4096*1024] f16 (dead after gemm1)
#define OFF_W2T  OFF_XG                    // u16[8*1024*4096] f16, ALIASES Xg+W1t
#define OFF_HB   (OFF_W1T + 67108864)      // u16[17408*4096] f16
// end = 245,891,072 bytes

__global__ void k_zero_out(float* __restrict__ out) {
  size_t i = (size_t)(blockIdx.x * 256 + threadIdx.x) * 4;
  *(f32x4*)&out[i] = (f32x4){0.f, 0.f, 0.f, 0.f};
}

__global__ void k_init(int* __restrict__ atok, float* __restrict__ wslot,
                       int* __restrict__ meta) {
  int i = blockIdx.x * 256 + threadIdx.x;
  if (i < MAXR) { atok[i] = 0; wslot[i] = 0.f; }
  if (blockIdx.x == 0 && threadIdx.x < 64) meta[threadIdx.x] = 0;
}

__global__ __launch_bounds__(256) void k_gate(
    const float* __restrict__ x, const float* __restrict__ Wg,
    const float* __restrict__ bg, int* __restrict__ counts,
    float* __restrict__ usage, int* __restrict__ topi, float* __restrict__ topw) {
  __shared__ float su[E_];
  if (threadIdx.x < E_) su[threadIdx.x] = 0.f;
  __syncthreads();
  const int lane = threadIdx.x & 63;
  const int b = blockIdx.x * 4 + (threadIdx.x >> 6);
  float p[E_] = {0.f,0.f,0.f,0.f,0.f,0.f,0.f,0.f};
  #pragma unroll
  for (int j = 0; j < 4; ++j) {
    int d = j * 256 + lane * 4;
    float4 xv = *(const float4*)&x[(size_t)b * D_ + d];
    const float* wr = &Wg[(size_t)d * E_];
    #pragma unroll
    for (int c = 0; c < 4; ++c) {
      float xc = reinterpret_cast<const float*>(&xv)[c];
      #pragma unroll
      for (int e = 0; e < E_; ++e) p[e] += xc * wr[c * E_ + e];
    }
  }
  #pragma unroll
  for (int off = 32; off >= 1; off >>= 1)
    #pragma unroll
    for (int e = 0; e < E_; ++e) p[e] += __shfl_xor(p[e], off, 64);
  float mx = -1e30f;
  #pragma unroll
  for (int e = 0; e < E_; ++e) { p[e] += bg[e]; mx = fmaxf(mx, p[e]); }
  int i0 = 0; float l0 = p[0];
  #pragma unroll
  for (int e = 1; e < E_; ++e) if (p[e] > l0) { l0 = p[e]; i0 = e; }
  int i1 = -1; float l1 = -1e30f;
  #pragma unroll
  for (int e = 0; e < E_; ++e) if (e != i0 && p[e] > l1) { l1 = p[e]; i1 = e; }
  float s = 0.f;
  #pragma unroll
  for (int e = 0; e < E_; ++e) { p[e] = expf(p[e] - mx); s += p[e]; }
  float inv = 1.f / s;
  if (lane == 0) {
    float e0 = expf(l0 - mx), e1 = expf(l1 - mx);
    float wsum = e0 + e1;
    topi[b * 2] = i0; topi[b * 2 + 1] = i1;
    topw[b * 2] = e0 / wsum; topw[b * 2 + 1] = e1 / wsum;
    atomicAdd(&counts[i0], 1);
    atomicAdd(&counts[i1], 1);
    #pragma unroll
    for (int e = 0; e < E_; ++e) atomicAdd(&su[e], p[e] * inv);
  }
  __syncthreads();
  if (threadIdx.x < E_) atomicAdd(&usage[threadIdx.x], su[threadIdx.x]);
}

__global__ void k_scan_aux(const int* __restrict__ counts, int* __restrict__ offsets,
                           const float* __restrict__ usage, float* __restrict__ auxp) {
  if (threadIdx.x == 0) {
    int off = 0;
    for (int e = 0; e < E_; ++e) { offsets[e] = off; off += (counts[e] + 127) & ~127; }
    offsets[E_] = off;
    float aux = 0.f;
    const float lu = logf(1.0f / (float)E_);
    for (int e = 0; e < E_; ++e) {
      float u = usage[e] * (1.0f / (float)B_);
      aux += u * lu - logf(u) * (1.0f / (float)E_);
    }
    *auxp = aux;
  }
}

__global__ void k_scatter(const int* __restrict__ topi, const float* __restrict__ topw,
                          const int* __restrict__ offsets, int* __restrict__ cursors,
                          int* __restrict__ atok, float* __restrict__ wslot) {
  int b = blockIdx.x * 256 + threadIdx.x;
  if (b >= B_) return;
  #pragma unroll
  for (int k = 0; k < 2; ++k) {
    int e = topi[b * 2 + k];
    int pos = atomicAdd(&cursors[e], 1);
    int slot = offsets[e] + pos;
    atok[slot] = b;
    wslot[slot] = topw[b * 2 + k];
  }
}

__global__ __launch_bounds__(256) void k_gather(const float* __restrict__ x,
                                                const int* __restrict__ atok,
                                                u16* __restrict__ Xg) {
  int slot = blockIdx.x;
  int tok = atok[slot];
  int c = threadIdx.x * 4;
  float4 v = *(const float4*)&x[(size_t)tok * D_ + c];
  const float* vf = reinterpret_cast<const float*>(&v);
  u16x4 o;
  o.x = f2h_bits(vf[0]); o.y = f2h_bits(vf[1]);
  o.z = f2h_bits(vf[2]); o.w = f2h_bits(vf[3]);
  *(u16x4*)&Xg[(size_t)slot * D_ + c] = o;
}

// convert + transpose: src [E][K][N] fp32  ->  dst [E][N][K] f16. 64x64 tiles.
__global__ __launch_bounds__(256) void k_cvt_t(const float* __restrict__ src,
                                               u16* __restrict__ dst, int K, int N) {
  const int e = blockIdx.z;
  const int kt = blockIdx.x * 64;
  const int nt = blockIdx.y * 64;
  __shared__ u16 t[64][68];
  const float* s = src + (size_t)e * K * N;
  u16* d = dst + (size_t)e * N * K;
  const int tr = threadIdx.x >> 4;
  const int tc = threadIdx.x & 15;
  #pragma unroll
  for (int i = 0; i < 4; ++i) {
    int k = tr + i * 16;
    float4 v = *(const float4*)&s[(size_t)(kt + k) * N + nt + tc * 4];
    t[k][tc*4+0] = f2h_bits(v.x); t[k][tc*4+1] = f2h_bits(v.y);
    t[k][tc*4+2] = f2h_bits(v.z); t[k][tc*4+3] = f2h_bits(v.w);
  }
  __syncthreads();
  #pragma unroll
  for (int i = 0; i < 4; ++i) {
    int n = tr + i * 16;
    u16x4 o;
    o.x = t[tc*4+0][n]; o.y = t[tc*4+1][n];
    o.z = t[tc*4+2][n]; o.w = t[tc*4+3][n];
    *(u16x4*)&d[(size_t)(nt + n) * K + kt + tc * 4] = o;
  }
}

#define GLDS(g, l) __builtin_amdgcn_global_load_lds( \
    (const u32 __attribute__((address_space(1)))*)(g), \
    (u32 __attribute__((address_space(3)))*)(l), 16, 0, 0)

// stage one 128x64 A-tile and 128x64 B-tile (f16) via global_load_lds w16.
// Named LDS arrays only — no dynamically-indexed pointers anywhere.
#define STG(Ap, Bp, LD, kk, Ad, Bd) do { \
  _Pragma("unroll") \
  for (int c = 0; c < 4; ++c) { \
    int seg = wid * 4 + c; \
    GLDS((Ap) + (size_t)(seg * 8 + srow) * (LD) + (kk) + scol, (Ad) + seg * 512); \
    GLDS((Bp) + (size_t)(seg * 8 + srow) * (LD) + (kk) + scol, (Bd) + seg * 512); \
  } } while (0)

#define CMP(As, Bs) do { \
  _Pragma("unroll") \
  for (int ks = 0; ks < 2; ++ks) { \
    f16x8 af[4], bf[4]; \
    _Pragma("unroll") \
    for (int m = 0; m < 4; ++m) \
      af[m] = *(const f16x8*)&(As)[(wr * 64 + m * 16 + (lane & 15)) * 64 + ks * 32 + (lane >> 4) * 8]; \
    _Pragma("unroll") \
    for (int n = 0; n < 4; ++n) \
      bf[n] = *(const f16x8*)&(Bs)[(wc * 64 + n * 16 + (lane & 15)) * 64 + ks * 32 + (lane >> 4) * 8]; \
    _Pragma("unroll") \
    for (int m = 0; m < 4; ++m) \
      _Pragma("unroll") \
      for (int n = 0; n < 4; ++n) \
        acc[m][n] = __builtin_amdgcn_mfma_f32_16x16x32_f16(af[m], bf[n], acc[m][n], 0, 0, 0); \
  } } while (0)

// GEMM1: Hb[slot][n] = gelu( Xg[slot][:] @ W1t[e][n][:]^T + b1[e][n] )  (f16 out)
// 128x128 tile, BK=64, double-buffered (named buffers), issue-early prefetch.
__global__ __launch_bounds__(256) void k_gemm1(
    const u16* __restrict__ Xg, const u16* __restrict__ W1t,
    const float* __restrict__ b1, const int* __restrict__ offsets,
    u16* __restrict__ Hb) {
  const int e  = blockIdx.x >> 6;
  const int mt = blockIdx.x & 63;
  const int roff = offsets[e];
  const int pn = offsets[e + 1] - roff;
  const int row0 = mt * 128;
  if (row0 >= pn) return;
  const int n0 = blockIdx.y * 128;
  const int tid = threadIdx.x, lane = tid & 63, wid = tid >> 6;
  const int wr = wid >> 1, wc = wid & 1;
  __shared__ __align__(16) u16 As0[8192], Bs0[8192], As1[8192], Bs1[8192];
  f32x4 acc[4][4] = {};
  const u16* Ap = Xg + (size_t)(roff + row0) * D_;
  const u16* Bp = W1t + (size_t)e * H_ * D_ + (size_t)n0 * D_;
  const int srow = lane >> 3;
  const int scol = (lane & 7) * 8;

  STG(Ap, Bp, D_, 0, As0, Bs0);
  __syncthreads();
  for (int kk = 0; kk < D_; kk += 128) {
    STG(Ap, Bp, D_, kk + 64, As1, Bs1);          // kk+64 <= 960 < D_ always
    CMP(As0, Bs0);
    __syncthreads();
    if (kk + 128 < D_) STG(Ap, Bp, D_, kk + 128, As0, Bs0);
    CMP(As1, Bs1);
    __syncthreads();
  }
  const int rhi = (lane >> 4) * 4, cix = lane & 15;
  #pragma unroll
  for (int n = 0; n < 4; ++n) {
    int lc = wc * 64 + n * 16 + cix;
    float bv = b1[e * H_ + n0 + lc];
    #pragma unroll
    for (int m = 0; m < 4; ++m) {
      #pragma unroll
      for (int j = 0; j < 4; ++j) {
        int lr = wr * 64 + m * 16 + rhi + j;
        Hb[(size_t)(roff + row0 + lr) * H_ + (n0 + lc)] = f2h_bits(gelu_f(acc[m][n][j] + bv));
      }
    }
  }
}

// GEMM2: out[tok][n] += wslot * ( Hb[slot][:] @ W2t[e][n][:]^T + b2[e][n] )
__global__ __launch_bounds__(256) void k_gemm2(
    const u16* __restrict__ Hb, const u16* __restrict__ W2t,
    const float* __restrict__ b2, const int* __restrict__ offsets,
    const int* __restrict__ atok, const float* __restrict__ wslot,
    float* __restrict__ out) {
  const int e  = blockIdx.x >> 6;
  const int mt = blockIdx.x & 63;
  const int roff = offsets[e];
  const int pn = offsets[e + 1] - roff;
  const int row0 = mt * 128;
  if (row0 >= pn) return;
  const int n0 = blockIdx.y * 128;
  const int tid = threadIdx.x, lane = tid & 63, wid = tid >> 6;
  const int wr = wid >> 1, wc = wid & 1;
  __shared__ __align__(16) u16 As0[8192], Bs0[8192], As1[8192], Bs1[8192];
  f32x4 acc[4][4] = {};
  const u16* Ap = Hb + (size_t)(roff + row0) * H_;
  const u16* Bp = W2t + (size_t)e * DOUT_ * H_ + (size_t)n0 * H_;
  const int srow = lane >> 3;
  const int scol = (lane & 7) * 8;

  STG(Ap, Bp, H_, 0, As0, Bs0);
  __syncthreads();
  for (int kk = 0; kk < H_; kk += 128) {
    STG(Ap, Bp, H_, kk + 64, As1, Bs1);          // kk+64 <= 4032 < H_ always
    CMP(As0, Bs0);
    __syncthreads();
    if (kk + 128 < H_) STG(Ap, Bp, H_, kk + 128, As0, Bs0);
    CMP(As1, Bs1);
    __syncthreads();
  }
  const int rhi = (lane >> 4) * 4, cix = lane & 15;
  float bv[4];
  #pragma unroll
  for (int n = 0; n < 4; ++n) bv[n] = b2[e * DOUT_ + n0 + wc * 64 + n * 16 + cix];
  #pragma unroll
  for (int m = 0; m < 4; ++m) {
    #pragma unroll
    for (int j = 0; j < 4; ++j) {
      int lr = wr * 64 + m * 16 + rhi + j;
      int slot = roff + row0 + lr;
      float w = wslot[slot];
      if (w == 0.f) continue;   // padding slot
      int tok = atok[slot];
      float* orow = out + (size_t)tok * DOUT_ + n0;
      #pragma unroll
      for (int n = 0; n < 4; ++n) {
        int lc = wc * 64 + n * 16 + cix;
        atomicAdd(&orow[lc], w * (acc[m][n][j] + bv[n]));
      }
    }
  }
}

extern "C" void kernel_launch(void* const* d_in, const int* in_sizes, int n_in,
                              void* d_out, int out_size, void* d_ws, size_t ws_size,
                              hipStream_t stream) {
  const float* x  = (const float*)d_in[0];
  const float* Wg = (const float*)d_in[1];
  const float* bg = (const float*)d_in[2];
  const float* W1 = (const float*)d_in[3];
  const float* b1 = (const float*)d_in[4];
  const float* W2 = (const float*)d_in[5];
  const float* b2 = (const float*)d_in[6];
  float* out = (float*)d_out;

  char* ws = (char*)d_ws;
  int*   counts  = (int*)(ws + 0);
  int*   cursors = (int*)(ws + 32);
  int*   offsets = (int*)(ws + 64);
  float* usage   = (float*)(ws + 128);
  int*   topi    = (int*)(ws + OFF_TOPI);
  float* topw    = (float*)(ws + OFF_TOPW);
  int*   atok    = (int*)(ws + OFF_ATOK);
  float* wslot   = (float*)(ws + OFF_WSL);
  u16*   Xg      = (u16*)(ws + OFF_XG);
  u16*   W1t     = (u16*)(ws + OFF_W1T);
  u16*   W2t     = (u16*)(ws + OFF_W2T);
  u16*   Hb      = (u16*)(ws + OFF_HB);

  k_zero_out<<<B_ * DOUT_ / 1024, 256, 0, stream>>>(out);
  k_init<<<(MAXR + 255) / 256, 256, 0, stream>>>(atok, wslot, (int*)ws);
  k_gate<<<B_ / 4, 256, 0, stream>>>(x, Wg, bg, counts, usage, topi, topw);
  k_scan_aux<<<1, 64, 0, stream>>>(counts, offsets, usage, out + (size_t)B_ * DOUT_);
  k_scatter<<<B_ / 256, 256, 0, stream>>>(topi, topw, offsets, cursors, atok, wslot);
  k_gather<<<MAXR, 256, 0, stream>>>(x, atok, Xg);
  k_cvt_t<<<dim3(D_ / 64, H_ / 64, E_), 256, 0, stream>>>(W1, W1t, D_, H_);
  k_gemm1<<<dim3(E_ * 64, H_ / 128), 256, 0, stream>>>(Xg, W1t, b1, offsets, Hb);
  k_cvt_t<<<dim3(H_ / 64, DOUT_ / 64, E_), 256, 0, stream>>>(W2, W2t, H_, DOUT_);
  k_gemm2<<<dim3(E_ * 64, DOUT_ / 128), 256, 0, stream>>>(Hb, W2t, b2, offsets, atok, wslot, out);
}